// Round 3
// baseline (218.392 us; speedup 1.0000x reference)
//
#include <hip/hip_runtime.h>
#include <math.h>

#define BN 2
#define SN 1024
#define TN 1024
#define DS 128
#define DT 64
#define HN 64
#define LN_EPS 1e-5f

__device__ __forceinline__ float wave_sum(float v) {
#pragma unroll
  for (int m = 32; m >= 1; m >>= 1) v += __shfl_xor(v, m, 64);
  return v;
}

// ---------------- Kernel 1: both adapters in one launch ----------------
__global__ __launch_bounds__(256) void k_adapters(
    const float* __restrict__ src, const float* __restrict__ tgt,
    const float* __restrict__ sW1, const float* __restrict__ sb1,
    const float* __restrict__ sg, const float* __restrict__ sbeta,
    const float* __restrict__ sW2, const float* __restrict__ sb2,
    const float* __restrict__ tW1, const float* __restrict__ tb1,
    const float* __restrict__ tg, const float* __restrict__ tbeta,
    const float* __restrict__ tW2, const float* __restrict__ tb2,
    const float* __restrict__ cW, const float* __restrict__ cb,
    float* __restrict__ s_ad, float* __restrict__ sc, float* __restrict__ sstats,
    float* __restrict__ t_ad, float* __restrict__ tc, float* __restrict__ tstats)
{
  __shared__ float xbuf[4][DS];
  __shared__ float rbuf[4][HN];
  int w = threadIdx.x >> 6, lane = threadIdx.x & 63;

  if (blockIdx.x < 512) {
    int row = blockIdx.x * 4 + w;  // 0..2047
    xbuf[w][lane]      = src[row * DS + lane];
    xbuf[w][lane + 64] = src[row * DS + 64 + lane];
    float a0 = 0.f, a1 = 0.f, a2_ = 0.f, a3 = 0.f;
#pragma unroll 8
    for (int k = 0; k < DS; k += 4) {
      a0  = fmaf(xbuf[w][k + 0], sW1[(k + 0) * HN + lane], a0);
      a1  = fmaf(xbuf[w][k + 1], sW1[(k + 1) * HN + lane], a1);
      a2_ = fmaf(xbuf[w][k + 2], sW1[(k + 2) * HN + lane], a2_);
      a3  = fmaf(xbuf[w][k + 3], sW1[(k + 3) * HN + lane], a3);
    }
    float h1 = ((a0 + a1) + (a2_ + a3)) + sb1[lane];
    float s1 = wave_sum(h1), s2 = wave_sum(h1 * h1);
    float m = s1 * (1.f / HN);
    float var = s2 * (1.f / HN) - m * m;
    float r = fmaxf(0.f, (h1 - m) * rsqrtf(var + LN_EPS) * sg[lane] + sbeta[lane]);
    rbuf[w][lane] = r;
    float b0 = 0.f, b1 = 0.f, b2 = 0.f, b3 = 0.f;
#pragma unroll 4
    for (int j = 0; j < HN; j += 4) {
      b0 = fmaf(rbuf[w][j + 0], sW2[(j + 0) * HN + lane], b0);
      b1 = fmaf(rbuf[w][j + 1], sW2[(j + 1) * HN + lane], b1);
      b2 = fmaf(rbuf[w][j + 2], sW2[(j + 2) * HN + lane], b2);
      b3 = fmaf(rbuf[w][j + 3], sW2[(j + 3) * HN + lane], b3);
    }
    float a2 = ((b0 + b1) + (b2 + b3)) + sb2[lane];
    s_ad[row * HN + lane] = a2;
    rbuf[w][lane] = a2;
    float c0 = 0.f, c1 = 0.f, c2 = 0.f, c3 = 0.f;
#pragma unroll 4
    for (int j = 0; j < HN; j += 4) {
      c0 = fmaf(rbuf[w][j + 0], cW[(HN + j + 0) * HN + lane], c0);
      c1 = fmaf(rbuf[w][j + 1], cW[(HN + j + 1) * HN + lane], c1);
      c2 = fmaf(rbuf[w][j + 2], cW[(HN + j + 2) * HN + lane], c2);
      c3 = fmaf(rbuf[w][j + 3], cW[(HN + j + 3) * HN + lane], c3);
    }
    float scv = (c0 + c1) + (c2 + c3);
    sc[row * HN + lane] = scv;
    float bs = wave_sum(scv), qs = wave_sum(scv * scv);
    if (lane == 0) { sstats[row * 2] = bs; sstats[row * 2 + 1] = qs; }
  } else {
    int row = (blockIdx.x - 512) * 4 + w;  // 0..2047
    xbuf[w][lane] = tgt[row * DT + lane];
    float a0 = 0.f, a1 = 0.f, a2_ = 0.f, a3 = 0.f;
#pragma unroll 4
    for (int k = 0; k < DT; k += 4) {
      a0  = fmaf(xbuf[w][k + 0], tW1[(k + 0) * HN + lane], a0);
      a1  = fmaf(xbuf[w][k + 1], tW1[(k + 1) * HN + lane], a1);
      a2_ = fmaf(xbuf[w][k + 2], tW1[(k + 2) * HN + lane], a2_);
      a3  = fmaf(xbuf[w][k + 3], tW1[(k + 3) * HN + lane], a3);
    }
    float h1 = ((a0 + a1) + (a2_ + a3)) + tb1[lane];
    float s1 = wave_sum(h1), s2 = wave_sum(h1 * h1);
    float m = s1 * (1.f / HN);
    float var = s2 * (1.f / HN) - m * m;
    float r = fmaxf(0.f, (h1 - m) * rsqrtf(var + LN_EPS) * tg[lane] + tbeta[lane]);
    rbuf[w][lane] = r;
    float b0 = 0.f, b1 = 0.f, b2 = 0.f, b3 = 0.f;
#pragma unroll 4
    for (int j = 0; j < HN; j += 4) {
      b0 = fmaf(rbuf[w][j + 0], tW2[(j + 0) * HN + lane], b0);
      b1 = fmaf(rbuf[w][j + 1], tW2[(j + 1) * HN + lane], b1);
      b2 = fmaf(rbuf[w][j + 2], tW2[(j + 2) * HN + lane], b2);
      b3 = fmaf(rbuf[w][j + 3], tW2[(j + 3) * HN + lane], b3);
    }
    float a2 = ((b0 + b1) + (b2 + b3)) + tb2[lane];
    t_ad[row * HN + lane] = a2;
    float asum = wave_sum(a2);
    float gate = 1.f / (1.f + __expf(-asum * (1.f / HN)));
    rbuf[w][lane] = a2;
    float c0 = 0.f, c1 = 0.f, c2 = 0.f, c3 = 0.f;
#pragma unroll 4
    for (int j = 0; j < HN; j += 4) {
      c0 = fmaf(rbuf[w][j + 0], cW[(j + 0) * HN + lane], c0);
      c1 = fmaf(rbuf[w][j + 1], cW[(j + 1) * HN + lane], c1);
      c2 = fmaf(rbuf[w][j + 2], cW[(j + 2) * HN + lane], c2);
      c3 = fmaf(rbuf[w][j + 3], cW[(j + 3) * HN + lane], c3);
    }
    float tcv = ((c0 + c1) + (c2 + c3)) + cb[lane];
    tc[row * HN + lane] = tcv;
    float A = wave_sum(tcv), Q = wave_sum(tcv * tcv);
    if (lane == 0) { tstats[row * 3] = A; tstats[row * 3 + 1] = Q; tstats[row * 3 + 2] = gate; }
  }
}

// ---------------- Kernel 2: scores v3 ----------------
// block = 16 t x 128 s. tile staged once to LDS, then per-lane s-row held in
// 16 float4 regs across the 8-t loop (2 LDS-insts/pair vs 32 before).
__global__ __launch_bounds__(256, 4) void k_scores(
    const float* __restrict__ cg, const float* __restrict__ cbeta,
    const float* __restrict__ simW, const float* __restrict__ simb,
    const float* __restrict__ sc, const float* __restrict__ sstats,
    const float* __restrict__ tc, const float* __restrict__ tstats,
    float* __restrict__ out_scores)
{
  __shared__ float tile[128 * 64];   // 32 KB, xor-swizzled rows
  int tid = threadIdx.x;
  int w = tid >> 6, lane = tid & 63;
  int sblk = blockIdx.x & 7;                 // 8 s-blocks of 128
  int tblk = (blockIdx.x >> 3) & 63;         // 64 t-blocks of 16
  int b    = blockIdx.x >> 9;
  int chunk = __builtin_amdgcn_readfirstlane(w & 1);   // which 64-s half
  int thalf = __builtin_amdgcn_readfirstlane(w >> 1);  // which 8-t half

  int s0 = sblk * 128;
  const float4* scg = (const float4*)(sc + b * SN * HN);

  // stage 128 x 64 tile (coalesced, xor swizzle)
#pragma unroll
  for (int it = 0; it < 8; ++it) {
    int j = it * 256 + tid;                  // 0..2047 float4s
    int srow = j >> 4, g = j & 15;
    float4 v = scg[(s0 + srow) * 16 + g];
    int gp = g ^ (srow & 15);
    *(float4*)&tile[srow * 64 + gp * 4] = v;
  }
  __syncthreads();

  // pull this lane's s-row into registers
  int srow = chunk * 64 + lane;
  float4 rr[16];
#pragma unroll
  for (int g = 0; g < 16; ++g)
    rr[g] = *(const float4*)&tile[srow * 64 + ((g ^ (srow & 15)) * 4)];

  int s = s0 + srow;
  float2 bq = *(const float2*)&sstats[(b * SN + s) * 2];
  float simb0 = simb[0];

#pragma unroll 2
  for (int tt = 0; tt < 8; ++tt) {
    int t = tblk * 16 + thalf * 8 + tt;
    int rt = __builtin_amdgcn_readfirstlane(b * TN + t);
    float A  = tstats[rt * 3 + 0];
    float Qt = tstats[rt * 3 + 1];
    const float* tcr = tc + rt * HN;

    // pass 1: D = sum_h tc_h * sc_h (from regs)
    float D0 = 0.f, D1 = 0.f, D2 = 0.f, D3 = 0.f;
#pragma unroll
    for (int g = 0; g < 16; ++g) {
      float4 v = rr[g];
      D0 = fmaf(tcr[g * 4 + 0], v.x, D0);
      D1 = fmaf(tcr[g * 4 + 1], v.y, D1);
      D2 = fmaf(tcr[g * 4 + 2], v.z, D2);
      D3 = fmaf(tcr[g * 4 + 3], v.w, D3);
    }
    float D = (D0 + D1) + (D2 + D3);
    float mean  = (A + bq.x) * (1.f / HN);
    float e2    = (Qt + bq.y + 2.f * D) * (1.f / HN);
    float var   = e2 - mean * mean;
    float alpha = rsqrtf(var + LN_EPS);

    // pass 2 (from regs)
    float dot0 = 0.f, dot1 = 0.f;
#pragma unroll
    for (int g = 0; g < 16; ++g) {
      float4 v = rr[g];
      int h = g * 4;
      {
        float P = alpha * cg[h + 0];
        float q = fmaf(-mean, P, cbeta[h + 0]);
        float n = fmaf(v.x + tcr[h + 0], P, q);
        dot0 = fmaf(fmaxf(n, 0.f), simW[h + 0], dot0);
      }
      {
        float P = alpha * cg[h + 1];
        float q = fmaf(-mean, P, cbeta[h + 1]);
        float n = fmaf(v.y + tcr[h + 1], P, q);
        dot1 = fmaf(fmaxf(n, 0.f), simW[h + 1], dot1);
      }
      {
        float P = alpha * cg[h + 2];
        float q = fmaf(-mean, P, cbeta[h + 2]);
        float n = fmaf(v.z + tcr[h + 2], P, q);
        dot0 = fmaf(fmaxf(n, 0.f), simW[h + 2], dot0);
      }
      {
        float P = alpha * cg[h + 3];
        float q = fmaf(-mean, P, cbeta[h + 3]);
        float n = fmaf(v.w + tcr[h + 3], P, q);
        dot1 = fmaf(fmaxf(n, 0.f), simW[h + 3], dot1);
      }
    }
    float dot = dot0 + dot1;
    float score = 1.f / (1.f + __expf(-(dot + simb0)));
    out_scores[rt * SN + s] = score;
  }
}

// ---------------- Kernel 3a: partial transfer (split-s) ----------------
// block = 16 t x 256 s; wave w owns s-sub [w*64, +64). s_ad loaded once per
// block, shared across 16 t. Writes per-(t,sblk) partial sums + exp-sums.
__global__ __launch_bounds__(256, 4) void k_xfer(
    const float* __restrict__ scores, const float* __restrict__ s_ad,
    float* __restrict__ xpart, float* __restrict__ epart)
{
  __shared__ float eLDS[4][16][64];   // 16 KB
  __shared__ float part[4][16][64];   // 16 KB
  __shared__ float esum[4][16];
  int tid = threadIdx.x;
  int w = __builtin_amdgcn_readfirstlane(tid >> 6);
  int lane = tid & 63;
  int sblk = blockIdx.x & 3;
  int tblk = (blockIdx.x >> 2) & 63;
  int b    = blockIdx.x >> 8;
  int t0 = tblk * 16;
  int soff = sblk * 256 + w * 64;

  // phase 1: exp(scores) into LDS + per-t partial expsum
#pragma unroll 4
  for (int t = 0; t < 16; ++t) {
    int rt = __builtin_amdgcn_readfirstlane(b * TN + t0 + t);
    float ev = __expf(scores[rt * SN + soff + lane]);
    eLDS[w][t][lane] = ev;
    float es = wave_sum(ev);
    if (lane == 0) esum[w][t] = es;
  }

  // phase 2: acc[t] += e[t,s] * s_ad[s, h=lane]  over this wave's 64 s
  const float* sadb = s_ad + b * SN * HN;
  float acc[16];
#pragma unroll
  for (int t = 0; t < 16; ++t) acc[t] = 0.f;
#pragma unroll 4
  for (int si4 = 0; si4 < 16; ++si4) {
    int sbase = soff + si4 * 4;
    float sv0 = sadb[(sbase + 0) * HN + lane];
    float sv1 = sadb[(sbase + 1) * HN + lane];
    float sv2 = sadb[(sbase + 2) * HN + lane];
    float sv3 = sadb[(sbase + 3) * HN + lane];
#pragma unroll
    for (int t = 0; t < 16; ++t) {
      float4 e4 = *(const float4*)&eLDS[w][t][si4 * 4];
      acc[t] = fmaf(e4.x, sv0, acc[t]);
      acc[t] = fmaf(e4.y, sv1, acc[t]);
      acc[t] = fmaf(e4.z, sv2, acc[t]);
      acc[t] = fmaf(e4.w, sv3, acc[t]);
    }
  }

  // phase 3: cross-wave reduce via LDS, write partials
#pragma unroll
  for (int t = 0; t < 16; ++t) part[w][t][lane] = acc[t];
  __syncthreads();
#pragma unroll
  for (int k = 0; k < 4; ++k) {
    int c2 = tid + k * 256;           // 0..1023 cells
    int t = c2 >> 6, h = c2 & 63;
    float sum = part[0][t][h] + part[1][t][h] + part[2][t][h] + part[3][t][h];
    int rt = b * TN + t0 + t;
    xpart[(rt * 4 + sblk) * HN + h] = sum;
  }
  if (tid < 16) {
    float es = esum[0][tid] + esum[1][tid] + esum[2][tid] + esum[3][tid];
    int rt = b * TN + t0 + tid;
    epart[rt * 4 + sblk] = es;
  }
}

// ---------------- Kernel 3b: final combine + gate ----------------
__global__ __launch_bounds__(256) void k_final(
    const float* __restrict__ xpart, const float* __restrict__ epart,
    const float* __restrict__ t_ad, const float* __restrict__ tstats,
    float* __restrict__ out_adapted)
{
  int tid = threadIdx.x;
  int tl = tid >> 6, h = tid & 63;
  int rt = blockIdx.x * 4 + tl;       // 0..2047
  float x = xpart[(rt * 4 + 0) * HN + h] + xpart[(rt * 4 + 1) * HN + h]
          + xpart[(rt * 4 + 2) * HN + h] + xpart[(rt * 4 + 3) * HN + h];
  float es = epart[rt * 4 + 0] + epart[rt * 4 + 1]
           + epart[rt * 4 + 2] + epart[rt * 4 + 3];
  float tr = x / es;
  float gate = tstats[rt * 3 + 2];
  float tad = t_ad[rt * HN + h];
  out_adapted[rt * HN + h] = tad * (1.f - gate) + tr * gate;
}

extern "C" void kernel_launch(void* const* d_in, const int* in_sizes, int n_in,
                              void* d_out, int out_size, void* d_ws, size_t ws_size,
                              hipStream_t stream) {
  const float* src   = (const float*)d_in[0];
  const float* tgt   = (const float*)d_in[1];
  const float* sW1   = (const float*)d_in[2];
  const float* sb1   = (const float*)d_in[3];
  const float* sg    = (const float*)d_in[4];
  const float* sbeta = (const float*)d_in[5];
  const float* sW2   = (const float*)d_in[6];
  const float* sb2   = (const float*)d_in[7];
  const float* tW1   = (const float*)d_in[8];
  const float* tb1   = (const float*)d_in[9];
  const float* tg    = (const float*)d_in[10];
  const float* tbeta = (const float*)d_in[11];
  const float* tW2   = (const float*)d_in[12];
  const float* tb2   = (const float*)d_in[13];
  const float* cW    = (const float*)d_in[14];
  const float* cb    = (const float*)d_in[15];
  const float* cg    = (const float*)d_in[16];
  const float* cbeta = (const float*)d_in[17];
  const float* simW  = (const float*)d_in[18];
  const float* simb  = (const float*)d_in[19];

  float* ws     = (float*)d_ws;
  float* s_ad   = ws;               // 131072
  float* sc     = ws + 131072;      // 131072
  float* sstats = ws + 262144;      // 4096
  float* t_ad   = ws + 266240;      // 131072
  float* tc     = ws + 397312;      // 131072
  float* tstats = ws + 528384;      // 6144
  float* xpart  = ws + 534528;      // 2048*4*64 = 524288
  float* epart  = ws + 1058816;     // 8192

  float* out_adapted = (float*)d_out;            // B*T*H
  float* out_scores  = (float*)d_out + 131072;   // B*T*S

  hipLaunchKernelGGL(k_adapters, dim3(1024), dim3(256), 0, stream,
                     src, tgt, sW1, sb1, sg, sbeta, sW2, sb2,
                     tW1, tb1, tg, tbeta, tW2, tb2, cW, cb,
                     s_ad, sc, sstats, t_ad, tc, tstats);
  hipLaunchKernelGGL(k_scores, dim3(BN * 64 * 8), dim3(256), 0, stream,
                     cg, cbeta, simW, simb, sc, sstats, tc, tstats, out_scores);
  hipLaunchKernelGGL(k_xfer, dim3(BN * 64 * 4), dim3(256), 0, stream,
                     out_scores, s_ad, xpart, epart);
  hipLaunchKernelGGL(k_final, dim3(512), dim3(256), 0, stream,
                     xpart, epart, t_ad, tstats, out_adapted);
}

// Round 4
// 182.871 us; speedup vs baseline: 1.1942x; 1.1942x over previous
//
#include <hip/hip_runtime.h>
#include <math.h>

#define BN 2
#define SN 1024
#define TN 1024
#define DS 128
#define DT 64
#define HN 64
#define LN_EPS 1e-5f

__device__ __forceinline__ float wave_sum(float v) {
#pragma unroll
  for (int m = 32; m >= 1; m >>= 1) v += __shfl_xor(v, m, 64);
  return v;
}

// ---------------- Kernel 1: both adapters in one launch ----------------
__global__ __launch_bounds__(256) void k_adapters(
    const float* __restrict__ src, const float* __restrict__ tgt,
    const float* __restrict__ sW1, const float* __restrict__ sb1,
    const float* __restrict__ sg, const float* __restrict__ sbeta,
    const float* __restrict__ sW2, const float* __restrict__ sb2,
    const float* __restrict__ tW1, const float* __restrict__ tb1,
    const float* __restrict__ tg, const float* __restrict__ tbeta,
    const float* __restrict__ tW2, const float* __restrict__ tb2,
    const float* __restrict__ cW, const float* __restrict__ cb,
    float* __restrict__ s_ad, float* __restrict__ sc, float* __restrict__ sstats,
    float* __restrict__ t_ad, float* __restrict__ tc, float* __restrict__ tstats)
{
  __shared__ float xbuf[4][DS];
  __shared__ float rbuf[4][HN];
  int w = threadIdx.x >> 6, lane = threadIdx.x & 63;

  if (blockIdx.x < 512) {
    int row = blockIdx.x * 4 + w;  // 0..2047
    xbuf[w][lane]      = src[row * DS + lane];
    xbuf[w][lane + 64] = src[row * DS + 64 + lane];
    float a0 = 0.f, a1 = 0.f, a2_ = 0.f, a3 = 0.f;
#pragma unroll 8
    for (int k = 0; k < DS; k += 4) {
      a0  = fmaf(xbuf[w][k + 0], sW1[(k + 0) * HN + lane], a0);
      a1  = fmaf(xbuf[w][k + 1], sW1[(k + 1) * HN + lane], a1);
      a2_ = fmaf(xbuf[w][k + 2], sW1[(k + 2) * HN + lane], a2_);
      a3  = fmaf(xbuf[w][k + 3], sW1[(k + 3) * HN + lane], a3);
    }
    float h1 = ((a0 + a1) + (a2_ + a3)) + sb1[lane];
    float s1 = wave_sum(h1), s2 = wave_sum(h1 * h1);
    float m = s1 * (1.f / HN);
    float var = s2 * (1.f / HN) - m * m;
    float r = fmaxf(0.f, (h1 - m) * rsqrtf(var + LN_EPS) * sg[lane] + sbeta[lane]);
    rbuf[w][lane] = r;
    float b0 = 0.f, b1 = 0.f, b2 = 0.f, b3 = 0.f;
#pragma unroll 4
    for (int j = 0; j < HN; j += 4) {
      b0 = fmaf(rbuf[w][j + 0], sW2[(j + 0) * HN + lane], b0);
      b1 = fmaf(rbuf[w][j + 1], sW2[(j + 1) * HN + lane], b1);
      b2 = fmaf(rbuf[w][j + 2], sW2[(j + 2) * HN + lane], b2);
      b3 = fmaf(rbuf[w][j + 3], sW2[(j + 3) * HN + lane], b3);
    }
    float a2 = ((b0 + b1) + (b2 + b3)) + sb2[lane];
    s_ad[row * HN + lane] = a2;
    rbuf[w][lane] = a2;
    float c0 = 0.f, c1 = 0.f, c2 = 0.f, c3 = 0.f;
#pragma unroll 4
    for (int j = 0; j < HN; j += 4) {
      c0 = fmaf(rbuf[w][j + 0], cW[(HN + j + 0) * HN + lane], c0);
      c1 = fmaf(rbuf[w][j + 1], cW[(HN + j + 1) * HN + lane], c1);
      c2 = fmaf(rbuf[w][j + 2], cW[(HN + j + 2) * HN + lane], c2);
      c3 = fmaf(rbuf[w][j + 3], cW[(HN + j + 3) * HN + lane], c3);
    }
    float scv = (c0 + c1) + (c2 + c3);
    sc[row * HN + lane] = scv;
    float bs = wave_sum(scv), qs = wave_sum(scv * scv);
    if (lane == 0) { sstats[row * 2] = bs; sstats[row * 2 + 1] = qs; }
  } else {
    int row = (blockIdx.x - 512) * 4 + w;  // 0..2047
    xbuf[w][lane] = tgt[row * DT + lane];
    float a0 = 0.f, a1 = 0.f, a2_ = 0.f, a3 = 0.f;
#pragma unroll 4
    for (int k = 0; k < DT; k += 4) {
      a0  = fmaf(xbuf[w][k + 0], tW1[(k + 0) * HN + lane], a0);
      a1  = fmaf(xbuf[w][k + 1], tW1[(k + 1) * HN + lane], a1);
      a2_ = fmaf(xbuf[w][k + 2], tW1[(k + 2) * HN + lane], a2_);
      a3  = fmaf(xbuf[w][k + 3], tW1[(k + 3) * HN + lane], a3);
    }
    float h1 = ((a0 + a1) + (a2_ + a3)) + tb1[lane];
    float s1 = wave_sum(h1), s2 = wave_sum(h1 * h1);
    float m = s1 * (1.f / HN);
    float var = s2 * (1.f / HN) - m * m;
    float r = fmaxf(0.f, (h1 - m) * rsqrtf(var + LN_EPS) * tg[lane] + tbeta[lane]);
    rbuf[w][lane] = r;
    float b0 = 0.f, b1 = 0.f, b2 = 0.f, b3 = 0.f;
#pragma unroll 4
    for (int j = 0; j < HN; j += 4) {
      b0 = fmaf(rbuf[w][j + 0], tW2[(j + 0) * HN + lane], b0);
      b1 = fmaf(rbuf[w][j + 1], tW2[(j + 1) * HN + lane], b1);
      b2 = fmaf(rbuf[w][j + 2], tW2[(j + 2) * HN + lane], b2);
      b3 = fmaf(rbuf[w][j + 3], tW2[(j + 3) * HN + lane], b3);
    }
    float a2 = ((b0 + b1) + (b2 + b3)) + tb2[lane];
    t_ad[row * HN + lane] = a2;
    float asum = wave_sum(a2);
    float gate = 1.f / (1.f + __expf(-asum * (1.f / HN)));
    rbuf[w][lane] = a2;
    float c0 = 0.f, c1 = 0.f, c2 = 0.f, c3 = 0.f;
#pragma unroll 4
    for (int j = 0; j < HN; j += 4) {
      c0 = fmaf(rbuf[w][j + 0], cW[(j + 0) * HN + lane], c0);
      c1 = fmaf(rbuf[w][j + 1], cW[(j + 1) * HN + lane], c1);
      c2 = fmaf(rbuf[w][j + 2], cW[(j + 2) * HN + lane], c2);
      c3 = fmaf(rbuf[w][j + 3], cW[(j + 3) * HN + lane], c3);
    }
    float tcv = ((c0 + c1) + (c2 + c3)) + cb[lane];
    tc[row * HN + lane] = tcv;
    float A = wave_sum(tcv), Q = wave_sum(tcv * tcv);
    if (lane == 0) { tstats[row * 3] = A; tstats[row * 3 + 1] = Q; tstats[row * 3 + 2] = gate; }
  }
}

// ---------------- Kernel 2: scores v4 ----------------
// 512-thread block = 8 waves = 8 t (ONE t per wave: tc row + consts live in
// SGPRs, hoisted once). Block covers 8 t x 256 s via 2 staged chunks of
// 128 s (32 KB LDS, xor swizzle). 4 barriers/block over 2048 pairs.
__global__ __launch_bounds__(512, 4) void k_scores(
    const float* __restrict__ cg, const float* __restrict__ cbeta,
    const float* __restrict__ simW, const float* __restrict__ simb,
    const float* __restrict__ sc, const float* __restrict__ sstats,
    const float* __restrict__ tc, const float* __restrict__ tstats,
    float* __restrict__ out_scores)
{
  __shared__ float tile[128 * 64];   // 32 KB
  int tid = threadIdx.x;
  int w = tid >> 6, lane = tid & 63;
  int sblk = blockIdx.x & 3;                 // 4 s-blocks of 256
  int tblk = (blockIdx.x >> 2) & 127;        // 128 t-blocks of 8
  int b    = blockIdx.x >> 9;
  int t = tblk * 8 + w;
  int rt = __builtin_amdgcn_readfirstlane(b * TN + t);

  float A  = tstats[rt * 3 + 0];
  float Qt = tstats[rt * 3 + 1];
  const float* tcr = tc + rt * HN;           // wave-uniform, hoisted to SGPRs
  float simb0 = simb[0];

  const float4* scg = (const float4*)(sc + b * SN * HN);

#pragma unroll 1
  for (int c = 0; c < 2; ++c) {
    int s0 = sblk * 256 + c * 128;
    __syncthreads();
    // stage 128 s-rows x 64 h (2048 float4s, 4 per thread), xor swizzle
#pragma unroll
    for (int it = 0; it < 4; ++it) {
      int j = it * 512 + tid;
      int srow = j >> 4, g = j & 15;
      float4 v = scg[(s0 + srow) * 16 + g];
      int gp = g ^ (srow & 15);
      *(float4*)&tile[srow * 64 + gp * 4] = v;
    }
    __syncthreads();

#pragma unroll 1
    for (int half = 0; half < 2; ++half) {
      int srow = half * 64 + lane;
      int s = s0 + srow;
      float2 bq = *(const float2*)&sstats[(b * SN + s) * 2];

      // pass 1: D = sum_h tc_h * sc_h
      float D0 = 0.f, D1 = 0.f, D2 = 0.f, D3 = 0.f;
#pragma unroll
      for (int g = 0; g < 16; ++g) {
        int gp = g ^ (srow & 15);
        float4 v = *(const float4*)&tile[srow * 64 + gp * 4];
        D0 = fmaf(tcr[g * 4 + 0], v.x, D0);
        D1 = fmaf(tcr[g * 4 + 1], v.y, D1);
        D2 = fmaf(tcr[g * 4 + 2], v.z, D2);
        D3 = fmaf(tcr[g * 4 + 3], v.w, D3);
      }
      float D = (D0 + D1) + (D2 + D3);
      float mean  = (A + bq.x) * (1.f / HN);
      float e2    = (Qt + bq.y + 2.f * D) * (1.f / HN);
      float var   = e2 - mean * mean;
      float alpha = rsqrtf(var + LN_EPS);

      // pass 2
      float dot0 = 0.f, dot1 = 0.f;
#pragma unroll
      for (int g = 0; g < 16; ++g) {
        int gp = g ^ (srow & 15);
        float4 v = *(const float4*)&tile[srow * 64 + gp * 4];
        int h = g * 4;
        {
          float P = alpha * cg[h + 0];
          float q = fmaf(-mean, P, cbeta[h + 0]);
          float n = fmaf(v.x + tcr[h + 0], P, q);
          dot0 = fmaf(fmaxf(n, 0.f), simW[h + 0], dot0);
        }
        {
          float P = alpha * cg[h + 1];
          float q = fmaf(-mean, P, cbeta[h + 1]);
          float n = fmaf(v.y + tcr[h + 1], P, q);
          dot1 = fmaf(fmaxf(n, 0.f), simW[h + 1], dot1);
        }
        {
          float P = alpha * cg[h + 2];
          float q = fmaf(-mean, P, cbeta[h + 2]);
          float n = fmaf(v.z + tcr[h + 2], P, q);
          dot0 = fmaf(fmaxf(n, 0.f), simW[h + 2], dot0);
        }
        {
          float P = alpha * cg[h + 3];
          float q = fmaf(-mean, P, cbeta[h + 3]);
          float n = fmaf(v.w + tcr[h + 3], P, q);
          dot1 = fmaf(fmaxf(n, 0.f), simW[h + 3], dot1);
        }
      }
      float dot = dot0 + dot1;
      float score = 1.f / (1.f + __expf(-(dot + simb0)));
      out_scores[rt * SN + s] = score;
    }
  }
}

// ---------------- Kernel 3a: partial transfer (split-s) ----------------
__global__ __launch_bounds__(256, 4) void k_xfer(
    const float* __restrict__ scores, const float* __restrict__ s_ad,
    float* __restrict__ xpart, float* __restrict__ epart)
{
  __shared__ float eLDS[4][16][64];
  __shared__ float part[4][16][64];
  __shared__ float esum[4][16];
  int tid = threadIdx.x;
  int w = __builtin_amdgcn_readfirstlane(tid >> 6);
  int lane = tid & 63;
  int sblk = blockIdx.x & 3;
  int tblk = (blockIdx.x >> 2) & 63;
  int b    = blockIdx.x >> 8;
  int t0 = tblk * 16;
  int soff = sblk * 256 + w * 64;

#pragma unroll 4
  for (int t = 0; t < 16; ++t) {
    int rt = __builtin_amdgcn_readfirstlane(b * TN + t0 + t);
    float ev = __expf(scores[rt * SN + soff + lane]);
    eLDS[w][t][lane] = ev;
    float es = wave_sum(ev);
    if (lane == 0) esum[w][t] = es;
  }

  const float* sadb = s_ad + b * SN * HN;
  float acc[16];
#pragma unroll
  for (int t = 0; t < 16; ++t) acc[t] = 0.f;
#pragma unroll 4
  for (int si4 = 0; si4 < 16; ++si4) {
    int sbase = soff + si4 * 4;
    float sv0 = sadb[(sbase + 0) * HN + lane];
    float sv1 = sadb[(sbase + 1) * HN + lane];
    float sv2 = sadb[(sbase + 2) * HN + lane];
    float sv3 = sadb[(sbase + 3) * HN + lane];
#pragma unroll
    for (int t = 0; t < 16; ++t) {
      float4 e4 = *(const float4*)&eLDS[w][t][si4 * 4];
      acc[t] = fmaf(e4.x, sv0, acc[t]);
      acc[t] = fmaf(e4.y, sv1, acc[t]);
      acc[t] = fmaf(e4.z, sv2, acc[t]);
      acc[t] = fmaf(e4.w, sv3, acc[t]);
    }
  }

#pragma unroll
  for (int t = 0; t < 16; ++t) part[w][t][lane] = acc[t];
  __syncthreads();
#pragma unroll
  for (int k = 0; k < 4; ++k) {
    int c2 = tid + k * 256;
    int t = c2 >> 6, h = c2 & 63;
    float sum = part[0][t][h] + part[1][t][h] + part[2][t][h] + part[3][t][h];
    int rt = b * TN + t0 + t;
    xpart[(rt * 4 + sblk) * HN + h] = sum;
  }
  if (tid < 16) {
    float es = esum[0][tid] + esum[1][tid] + esum[2][tid] + esum[3][tid];
    int rt = b * TN + t0 + tid;
    epart[rt * 4 + sblk] = es;
  }
}

// ---------------- Kernel 3b: final combine + gate ----------------
__global__ __launch_bounds__(256) void k_final(
    const float* __restrict__ xpart, const float* __restrict__ epart,
    const float* __restrict__ t_ad, const float* __restrict__ tstats,
    float* __restrict__ out_adapted)
{
  int tid = threadIdx.x;
  int tl = tid >> 6, h = tid & 63;
  int rt = blockIdx.x * 4 + tl;       // 0..2047
  float x = xpart[(rt * 4 + 0) * HN + h] + xpart[(rt * 4 + 1) * HN + h]
          + xpart[(rt * 4 + 2) * HN + h] + xpart[(rt * 4 + 3) * HN + h];
  float es = epart[rt * 4 + 0] + epart[rt * 4 + 1]
           + epart[rt * 4 + 2] + epart[rt * 4 + 3];
  float tr = x / es;
  float gate = tstats[rt * 3 + 2];
  float tad = t_ad[rt * HN + h];
  out_adapted[rt * HN + h] = tad * (1.f - gate) + tr * gate;
}

extern "C" void kernel_launch(void* const* d_in, const int* in_sizes, int n_in,
                              void* d_out, int out_size, void* d_ws, size_t ws_size,
                              hipStream_t stream) {
  const float* src   = (const float*)d_in[0];
  const float* tgt   = (const float*)d_in[1];
  const float* sW1   = (const float*)d_in[2];
  const float* sb1   = (const float*)d_in[3];
  const float* sg    = (const float*)d_in[4];
  const float* sbeta = (const float*)d_in[5];
  const float* sW2   = (const float*)d_in[6];
  const float* sb2   = (const float*)d_in[7];
  const float* tW1   = (const float*)d_in[8];
  const float* tb1   = (const float*)d_in[9];
  const float* tg    = (const float*)d_in[10];
  const float* tbeta = (const float*)d_in[11];
  const float* tW2   = (const float*)d_in[12];
  const float* tb2   = (const float*)d_in[13];
  const float* cW    = (const float*)d_in[14];
  const float* cb    = (const float*)d_in[15];
  const float* cg    = (const float*)d_in[16];
  const float* cbeta = (const float*)d_in[17];
  const float* simW  = (const float*)d_in[18];
  const float* simb  = (const float*)d_in[19];

  float* ws     = (float*)d_ws;
  float* s_ad   = ws;               // 131072
  float* sc     = ws + 131072;      // 131072
  float* sstats = ws + 262144;      // 4096
  float* t_ad   = ws + 266240;      // 131072
  float* tc     = ws + 397312;      // 131072
  float* tstats = ws + 528384;      // 6144
  float* xpart  = ws + 534528;      // 524288
  float* epart  = ws + 1058816;     // 8192

  float* out_adapted = (float*)d_out;            // B*T*H
  float* out_scores  = (float*)d_out + 131072;   // B*T*S

  hipLaunchKernelGGL(k_adapters, dim3(1024), dim3(256), 0, stream,
                     src, tgt, sW1, sb1, sg, sbeta, sW2, sb2,
                     tW1, tb1, tg, tbeta, tW2, tb2, cW, cb,
                     s_ad, sc, sstats, t_ad, tc, tstats);
  hipLaunchKernelGGL(k_scores, dim3(BN * 128 * 4), dim3(512), 0, stream,
                     cg, cbeta, simW, simb, sc, sstats, tc, tstats, out_scores);
  hipLaunchKernelGGL(k_xfer, dim3(BN * 64 * 4), dim3(256), 0, stream,
                     out_scores, s_ad, xpart, epart);
  hipLaunchKernelGGL(k_final, dim3(512), dim3(256), 0, stream,
                     xpart, epart, t_ad, tstats, out_adapted);
}

// Round 5
// 181.781 us; speedup vs baseline: 1.2014x; 1.0060x over previous
//
#include <hip/hip_runtime.h>
#include <math.h>

#define BN 2
#define SN 1024
#define TN 1024
#define DS 128
#define DT 64
#define HN 64
#define LN_EPS 1e-5f

__device__ __forceinline__ float wave_sum(float v) {
#pragma unroll
  for (int m = 32; m >= 1; m >>= 1) v += __shfl_xor(v, m, 64);
  return v;
}

// ---------------- Kernel 1: both adapters in one launch ----------------
__global__ __launch_bounds__(256) void k_adapters(
    const float* __restrict__ src, const float* __restrict__ tgt,
    const float* __restrict__ sW1, const float* __restrict__ sb1,
    const float* __restrict__ sg, const float* __restrict__ sbeta,
    const float* __restrict__ sW2, const float* __restrict__ sb2,
    const float* __restrict__ tW1, const float* __restrict__ tb1,
    const float* __restrict__ tg, const float* __restrict__ tbeta,
    const float* __restrict__ tW2, const float* __restrict__ tb2,
    const float* __restrict__ cW, const float* __restrict__ cb,
    float* __restrict__ s_ad, float* __restrict__ sc, float* __restrict__ sstats,
    float* __restrict__ t_ad, float* __restrict__ tc, float* __restrict__ tstats)
{
  __shared__ float xbuf[4][DS];
  __shared__ float rbuf[4][HN];
  int w = threadIdx.x >> 6, lane = threadIdx.x & 63;

  if (blockIdx.x < 512) {
    int row = blockIdx.x * 4 + w;  // 0..2047
    xbuf[w][lane]      = src[row * DS + lane];
    xbuf[w][lane + 64] = src[row * DS + 64 + lane];
    float a0 = 0.f, a1 = 0.f, a2_ = 0.f, a3 = 0.f;
#pragma unroll 8
    for (int k = 0; k < DS; k += 4) {
      a0  = fmaf(xbuf[w][k + 0], sW1[(k + 0) * HN + lane], a0);
      a1  = fmaf(xbuf[w][k + 1], sW1[(k + 1) * HN + lane], a1);
      a2_ = fmaf(xbuf[w][k + 2], sW1[(k + 2) * HN + lane], a2_);
      a3  = fmaf(xbuf[w][k + 3], sW1[(k + 3) * HN + lane], a3);
    }
    float h1 = ((a0 + a1) + (a2_ + a3)) + sb1[lane];
    float s1 = wave_sum(h1), s2 = wave_sum(h1 * h1);
    float m = s1 * (1.f / HN);
    float var = s2 * (1.f / HN) - m * m;
    float r = fmaxf(0.f, (h1 - m) * rsqrtf(var + LN_EPS) * sg[lane] + sbeta[lane]);
    rbuf[w][lane] = r;
    float b0 = 0.f, b1 = 0.f, b2 = 0.f, b3 = 0.f;
#pragma unroll 4
    for (int j = 0; j < HN; j += 4) {
      b0 = fmaf(rbuf[w][j + 0], sW2[(j + 0) * HN + lane], b0);
      b1 = fmaf(rbuf[w][j + 1], sW2[(j + 1) * HN + lane], b1);
      b2 = fmaf(rbuf[w][j + 2], sW2[(j + 2) * HN + lane], b2);
      b3 = fmaf(rbuf[w][j + 3], sW2[(j + 3) * HN + lane], b3);
    }
    float a2 = ((b0 + b1) + (b2 + b3)) + sb2[lane];
    s_ad[row * HN + lane] = a2;
    rbuf[w][lane] = a2;
    float c0 = 0.f, c1 = 0.f, c2 = 0.f, c3 = 0.f;
#pragma unroll 4
    for (int j = 0; j < HN; j += 4) {
      c0 = fmaf(rbuf[w][j + 0], cW[(HN + j + 0) * HN + lane], c0);
      c1 = fmaf(rbuf[w][j + 1], cW[(HN + j + 1) * HN + lane], c1);
      c2 = fmaf(rbuf[w][j + 2], cW[(HN + j + 2) * HN + lane], c2);
      c3 = fmaf(rbuf[w][j + 3], cW[(HN + j + 3) * HN + lane], c3);
    }
    float scv = (c0 + c1) + (c2 + c3);
    sc[row * HN + lane] = scv;
    float bs = wave_sum(scv), qs = wave_sum(scv * scv);
    if (lane == 0) { sstats[row * 2] = bs; sstats[row * 2 + 1] = qs; }
  } else {
    int row = (blockIdx.x - 512) * 4 + w;  // 0..2047
    xbuf[w][lane] = tgt[row * DT + lane];
    float a0 = 0.f, a1 = 0.f, a2_ = 0.f, a3 = 0.f;
#pragma unroll 4
    for (int k = 0; k < DT; k += 4) {
      a0  = fmaf(xbuf[w][k + 0], tW1[(k + 0) * HN + lane], a0);
      a1  = fmaf(xbuf[w][k + 1], tW1[(k + 1) * HN + lane], a1);
      a2_ = fmaf(xbuf[w][k + 2], tW1[(k + 2) * HN + lane], a2_);
      a3  = fmaf(xbuf[w][k + 3], tW1[(k + 3) * HN + lane], a3);
    }
    float h1 = ((a0 + a1) + (a2_ + a3)) + tb1[lane];
    float s1 = wave_sum(h1), s2 = wave_sum(h1 * h1);
    float m = s1 * (1.f / HN);
    float var = s2 * (1.f / HN) - m * m;
    float r = fmaxf(0.f, (h1 - m) * rsqrtf(var + LN_EPS) * tg[lane] + tbeta[lane]);
    rbuf[w][lane] = r;
    float b0 = 0.f, b1 = 0.f, b2 = 0.f, b3 = 0.f;
#pragma unroll 4
    for (int j = 0; j < HN; j += 4) {
      b0 = fmaf(rbuf[w][j + 0], tW2[(j + 0) * HN + lane], b0);
      b1 = fmaf(rbuf[w][j + 1], tW2[(j + 1) * HN + lane], b1);
      b2 = fmaf(rbuf[w][j + 2], tW2[(j + 2) * HN + lane], b2);
      b3 = fmaf(rbuf[w][j + 3], tW2[(j + 3) * HN + lane], b3);
    }
    float a2 = ((b0 + b1) + (b2 + b3)) + tb2[lane];
    t_ad[row * HN + lane] = a2;
    float asum = wave_sum(a2);
    float gate = 1.f / (1.f + __expf(-asum * (1.f / HN)));
    rbuf[w][lane] = a2;
    float c0 = 0.f, c1 = 0.f, c2 = 0.f, c3 = 0.f;
#pragma unroll 4
    for (int j = 0; j < HN; j += 4) {
      c0 = fmaf(rbuf[w][j + 0], cW[(j + 0) * HN + lane], c0);
      c1 = fmaf(rbuf[w][j + 1], cW[(j + 1) * HN + lane], c1);
      c2 = fmaf(rbuf[w][j + 2], cW[(j + 2) * HN + lane], c2);
      c3 = fmaf(rbuf[w][j + 3], cW[(j + 3) * HN + lane], c3);
    }
    float tcv = ((c0 + c1) + (c2 + c3)) + cb[lane];
    tc[row * HN + lane] = tcv;
    float A = wave_sum(tcv), Q = wave_sum(tcv * tcv);
    if (lane == 0) { tstats[row * 3] = A; tstats[row * 3 + 1] = Q; tstats[row * 3 + 2] = gate; }
  }
}

// ---------------- Kernel 2: scores v5 ----------------
// R4 skeleton (8 waves, ONE t per wave, 2 staged 128-s chunks) but the
// s-row is pulled from LDS into 16 float4 VGPRs once per half; pass 1 is
// fused with the fill and pass 2 runs pure-register (no DS/SMEM interleave
// on lgkmcnt). Per-h math: y = fma(alpha, u, -alpha*mean) keeps <=1 SGPR
// per VALU instruction.
__global__ __launch_bounds__(512, 4) void k_scores(
    const float* __restrict__ cg, const float* __restrict__ cbeta,
    const float* __restrict__ simW, const float* __restrict__ simb,
    const float* __restrict__ sc, const float* __restrict__ sstats,
    const float* __restrict__ tc, const float* __restrict__ tstats,
    float* __restrict__ out_scores)
{
  __shared__ float tile[128 * 64];   // 32 KB
  int tid = threadIdx.x;
  int w = tid >> 6, lane = tid & 63;
  int sblk = blockIdx.x & 3;                 // 4 s-blocks of 256
  int tblk = (blockIdx.x >> 2) & 127;        // 128 t-blocks of 8
  int b    = blockIdx.x >> 9;
  int t = tblk * 8 + w;
  int rt = __builtin_amdgcn_readfirstlane(b * TN + t);

  float A  = tstats[rt * 3 + 0];
  float Qt = tstats[rt * 3 + 1];
  const float* tcr = tc + rt * HN;           // wave-uniform -> s_load
  float simb0 = simb[0];

  const float4* scg = (const float4*)(sc + b * SN * HN);

#pragma unroll 1
  for (int c = 0; c < 2; ++c) {
    int s0 = sblk * 256 + c * 128;
    __syncthreads();
    // stage 128 s-rows x 64 h (2048 float4s, 4/thread), xor swizzle
#pragma unroll
    for (int it = 0; it < 4; ++it) {
      int j = it * 512 + tid;
      int srow = j >> 4, g = j & 15;
      float4 v = scg[(s0 + srow) * 16 + g];
      int gp = g ^ (srow & 15);
      *(float4*)&tile[srow * 64 + gp * 4] = v;
    }
    __syncthreads();

#pragma unroll 1
    for (int half = 0; half < 2; ++half) {
      int srow = half * 64 + lane;
      int s = s0 + srow;
      float2 bq = *(const float2*)&sstats[(b * SN + s) * 2];

      // fill: 16 back-to-back ds_read_b128 into registers
      float4 rr[16];
#pragma unroll
      for (int g = 0; g < 16; ++g)
        rr[g] = *(const float4*)&tile[srow * 64 + ((g ^ (srow & 15)) * 4)];

      // pass 1 (from regs): D = sum_h tc_h * sc_h
      float D0 = 0.f, D1 = 0.f, D2 = 0.f, D3 = 0.f;
#pragma unroll
      for (int g = 0; g < 16; ++g) {
        float4 v = rr[g];
        D0 = fmaf(tcr[g * 4 + 0], v.x, D0);
        D1 = fmaf(tcr[g * 4 + 1], v.y, D1);
        D2 = fmaf(tcr[g * 4 + 2], v.z, D2);
        D3 = fmaf(tcr[g * 4 + 3], v.w, D3);
      }
      float D = (D0 + D1) + (D2 + D3);
      float mean  = (A + bq.x) * (1.f / HN);
      float e2    = (Qt + bq.y + 2.f * D) * (1.f / HN);
      float var   = e2 - mean * mean;
      float alpha = rsqrtf(var + LN_EPS);
      float mam   = -alpha * mean;          // per-pair fused constant

      // pass 2 (pure registers): n = (alpha*u + mam)*cg + cbeta
      float dot0 = 0.f, dot1 = 0.f;
#pragma unroll
      for (int g = 0; g < 16; ++g) {
        float4 v = rr[g];
        int h = g * 4;
        {
          float u = v.x + tcr[h + 0];
          float y = fmaf(alpha, u, mam);
          float n = fmaf(y, cg[h + 0], 0.f) + cbeta[h + 0];
          dot0 = fmaf(fmaxf(n, 0.f), simW[h + 0], dot0);
        }
        {
          float u = v.y + tcr[h + 1];
          float y = fmaf(alpha, u, mam);
          float n = fmaf(y, cg[h + 1], 0.f) + cbeta[h + 1];
          dot1 = fmaf(fmaxf(n, 0.f), simW[h + 1], dot1);
        }
        {
          float u = v.z + tcr[h + 2];
          float y = fmaf(alpha, u, mam);
          float n = fmaf(y, cg[h + 2], 0.f) + cbeta[h + 2];
          dot0 = fmaf(fmaxf(n, 0.f), simW[h + 2], dot0);
        }
        {
          float u = v.w + tcr[h + 3];
          float y = fmaf(alpha, u, mam);
          float n = fmaf(y, cg[h + 3], 0.f) + cbeta[h + 3];
          dot1 = fmaf(fmaxf(n, 0.f), simW[h + 3], dot1);
        }
      }
      float dot = dot0 + dot1;
      float score = 1.f / (1.f + __expf(-(dot + simb0)));
      out_scores[rt * SN + s] = score;
    }
  }
}

// ---------------- Kernel 3a: partial transfer (split-s) ----------------
__global__ __launch_bounds__(256, 4) void k_xfer(
    const float* __restrict__ scores, const float* __restrict__ s_ad,
    float* __restrict__ xpart, float* __restrict__ epart)
{
  __shared__ float eLDS[4][16][64];
  __shared__ float part[4][16][64];
  __shared__ float esum[4][16];
  int tid = threadIdx.x;
  int w = __builtin_amdgcn_readfirstlane(tid >> 6);
  int lane = tid & 63;
  int sblk = blockIdx.x & 3;
  int tblk = (blockIdx.x >> 2) & 63;
  int b    = blockIdx.x >> 8;
  int t0 = tblk * 16;
  int soff = sblk * 256 + w * 64;

#pragma unroll 4
  for (int t = 0; t < 16; ++t) {
    int rt = __builtin_amdgcn_readfirstlane(b * TN + t0 + t);
    float ev = __expf(scores[rt * SN + soff + lane]);
    eLDS[w][t][lane] = ev;
    float es = wave_sum(ev);
    if (lane == 0) esum[w][t] = es;
  }

  const float* sadb = s_ad + b * SN * HN;
  float acc[16];
#pragma unroll
  for (int t = 0; t < 16; ++t) acc[t] = 0.f;
#pragma unroll 4
  for (int si4 = 0; si4 < 16; ++si4) {
    int sbase = soff + si4 * 4;
    float sv0 = sadb[(sbase + 0) * HN + lane];
    float sv1 = sadb[(sbase + 1) * HN + lane];
    float sv2 = sadb[(sbase + 2) * HN + lane];
    float sv3 = sadb[(sbase + 3) * HN + lane];
#pragma unroll
    for (int t = 0; t < 16; ++t) {
      float4 e4 = *(const float4*)&eLDS[w][t][si4 * 4];
      acc[t] = fmaf(e4.x, sv0, acc[t]);
      acc[t] = fmaf(e4.y, sv1, acc[t]);
      acc[t] = fmaf(e4.z, sv2, acc[t]);
      acc[t] = fmaf(e4.w, sv3, acc[t]);
    }
  }

#pragma unroll
  for (int t = 0; t < 16; ++t) part[w][t][lane] = acc[t];
  __syncthreads();
#pragma unroll
  for (int k = 0; k < 4; ++k) {
    int c2 = tid + k * 256;
    int t = c2 >> 6, h = c2 & 63;
    float sum = part[0][t][h] + part[1][t][h] + part[2][t][h] + part[3][t][h];
    int rt = b * TN + t0 + t;
    xpart[(rt * 4 + sblk) * HN + h] = sum;
  }
  if (tid < 16) {
    float es = esum[0][tid] + esum[1][tid] + esum[2][tid] + esum[3][tid];
    int rt = b * TN + t0 + tid;
    epart[rt * 4 + sblk] = es;
  }
}

// ---------------- Kernel 3b: final combine + gate ----------------
__global__ __launch_bounds__(256) void k_final(
    const float* __restrict__ xpart, const float* __restrict__ epart,
    const float* __restrict__ t_ad, const float* __restrict__ tstats,
    float* __restrict__ out_adapted)
{
  int tid = threadIdx.x;
  int tl = tid >> 6, h = tid & 63;
  int rt = blockIdx.x * 4 + tl;       // 0..2047
  float x = xpart[(rt * 4 + 0) * HN + h] + xpart[(rt * 4 + 1) * HN + h]
          + xpart[(rt * 4 + 2) * HN + h] + xpart[(rt * 4 + 3) * HN + h];
  float es = epart[rt * 4 + 0] + epart[rt * 4 + 1]
           + epart[rt * 4 + 2] + epart[rt * 4 + 3];
  float tr = x / es;
  float gate = tstats[rt * 3 + 2];
  float tad = t_ad[rt * HN + h];
  out_adapted[rt * HN + h] = tad * (1.f - gate) + tr * gate;
}

extern "C" void kernel_launch(void* const* d_in, const int* in_sizes, int n_in,
                              void* d_out, int out_size, void* d_ws, size_t ws_size,
                              hipStream_t stream) {
  const float* src   = (const float*)d_in[0];
  const float* tgt   = (const float*)d_in[1];
  const float* sW1   = (const float*)d_in[2];
  const float* sb1   = (const float*)d_in[3];
  const float* sg    = (const float*)d_in[4];
  const float* sbeta = (const float*)d_in[5];
  const float* sW2   = (const float*)d_in[6];
  const float* sb2   = (const float*)d_in[7];
  const float* tW1   = (const float*)d_in[8];
  const float* tb1   = (const float*)d_in[9];
  const float* tg    = (const float*)d_in[10];
  const float* tbeta = (const float*)d_in[11];
  const float* tW2   = (const float*)d_in[12];
  const float* tb2   = (const float*)d_in[13];
  const float* cW    = (const float*)d_in[14];
  const float* cb    = (const float*)d_in[15];
  const float* cg    = (const float*)d_in[16];
  const float* cbeta = (const float*)d_in[17];
  const float* simW  = (const float*)d_in[18];
  const float* simb  = (const float*)d_in[19];

  float* ws     = (float*)d_ws;
  float* s_ad   = ws;               // 131072
  float* sc     = ws + 131072;      // 131072
  float* sstats = ws + 262144;      // 4096
  float* t_ad   = ws + 266240;      // 131072
  float* tc     = ws + 397312;      // 131072
  float* tstats = ws + 528384;      // 6144
  float* xpart  = ws + 534528;      // 524288
  float* epart  = ws + 1058816;     // 8192

  float* out_adapted = (float*)d_out;            // B*T*H
  float* out_scores  = (float*)d_out + 131072;   // B*T*S

  hipLaunchKernelGGL(k_adapters, dim3(1024), dim3(256), 0, stream,
                     src, tgt, sW1, sb1, sg, sbeta, sW2, sb2,
                     tW1, tb1, tg, tbeta, tW2, tb2, cW, cb,
                     s_ad, sc, sstats, t_ad, tc, tstats);
  hipLaunchKernelGGL(k_scores, dim3(BN * 128 * 4), dim3(512), 0, stream,
                     cg, cbeta, simW, simb, sc, sstats, tc, tstats, out_scores);
  hipLaunchKernelGGL(k_xfer, dim3(BN * 64 * 4), dim3(256), 0, stream,
                     out_scores, s_ad, xpart, epart);
  hipLaunchKernelGGL(k_final, dim3(512), dim3(256), 0, stream,
                     xpart, epart, t_ad, tstats, out_adapted);
}

// Round 6
// 169.327 us; speedup vs baseline: 1.2898x; 1.0736x over previous
//
#include <hip/hip_runtime.h>
#include <math.h>

#define BN 2
#define SN 1024
#define TN 1024
#define DS 128
#define DT 64
#define HN 64
#define LN_EPS 1e-5f

typedef float v2f __attribute__((ext_vector_type(2)));

__device__ __forceinline__ float wave_sum(float v) {
#pragma unroll
  for (int m = 32; m >= 1; m >>= 1) v += __shfl_xor(v, m, 64);
  return v;
}

// ---------------- Kernel 1: both adapters in one launch ----------------
__global__ __launch_bounds__(256) void k_adapters(
    const float* __restrict__ src, const float* __restrict__ tgt,
    const float* __restrict__ sW1, const float* __restrict__ sb1,
    const float* __restrict__ sg, const float* __restrict__ sbeta,
    const float* __restrict__ sW2, const float* __restrict__ sb2,
    const float* __restrict__ tW1, const float* __restrict__ tb1,
    const float* __restrict__ tg, const float* __restrict__ tbeta,
    const float* __restrict__ tW2, const float* __restrict__ tb2,
    const float* __restrict__ cW, const float* __restrict__ cb,
    float* __restrict__ s_ad, float* __restrict__ sc, float* __restrict__ sstats,
    float* __restrict__ t_ad, float* __restrict__ tc, float* __restrict__ tstats)
{
  __shared__ float xbuf[4][DS];
  __shared__ float rbuf[4][HN];
  int w = threadIdx.x >> 6, lane = threadIdx.x & 63;

  if (blockIdx.x < 512) {
    int row = blockIdx.x * 4 + w;  // 0..2047
    xbuf[w][lane]      = src[row * DS + lane];
    xbuf[w][lane + 64] = src[row * DS + 64 + lane];
    float a0 = 0.f, a1 = 0.f, a2_ = 0.f, a3 = 0.f;
#pragma unroll 8
    for (int k = 0; k < DS; k += 4) {
      a0  = fmaf(xbuf[w][k + 0], sW1[(k + 0) * HN + lane], a0);
      a1  = fmaf(xbuf[w][k + 1], sW1[(k + 1) * HN + lane], a1);
      a2_ = fmaf(xbuf[w][k + 2], sW1[(k + 2) * HN + lane], a2_);
      a3  = fmaf(xbuf[w][k + 3], sW1[(k + 3) * HN + lane], a3);
    }
    float h1 = ((a0 + a1) + (a2_ + a3)) + sb1[lane];
    float s1 = wave_sum(h1), s2 = wave_sum(h1 * h1);
    float m = s1 * (1.f / HN);
    float var = s2 * (1.f / HN) - m * m;
    float r = fmaxf(0.f, (h1 - m) * rsqrtf(var + LN_EPS) * sg[lane] + sbeta[lane]);
    rbuf[w][lane] = r;
    float b0 = 0.f, b1 = 0.f, b2 = 0.f, b3 = 0.f;
#pragma unroll 4
    for (int j = 0; j < HN; j += 4) {
      b0 = fmaf(rbuf[w][j + 0], sW2[(j + 0) * HN + lane], b0);
      b1 = fmaf(rbuf[w][j + 1], sW2[(j + 1) * HN + lane], b1);
      b2 = fmaf(rbuf[w][j + 2], sW2[(j + 2) * HN + lane], b2);
      b3 = fmaf(rbuf[w][j + 3], sW2[(j + 3) * HN + lane], b3);
    }
    float a2 = ((b0 + b1) + (b2 + b3)) + sb2[lane];
    s_ad[row * HN + lane] = a2;
    rbuf[w][lane] = a2;
    float c0 = 0.f, c1 = 0.f, c2 = 0.f, c3 = 0.f;
#pragma unroll 4
    for (int j = 0; j < HN; j += 4) {
      c0 = fmaf(rbuf[w][j + 0], cW[(HN + j + 0) * HN + lane], c0);
      c1 = fmaf(rbuf[w][j + 1], cW[(HN + j + 1) * HN + lane], c1);
      c2 = fmaf(rbuf[w][j + 2], cW[(HN + j + 2) * HN + lane], c2);
      c3 = fmaf(rbuf[w][j + 3], cW[(HN + j + 3) * HN + lane], c3);
    }
    float scv = (c0 + c1) + (c2 + c3);
    sc[row * HN + lane] = scv;
    float bs = wave_sum(scv), qs = wave_sum(scv * scv);
    if (lane == 0) { sstats[row * 2] = bs; sstats[row * 2 + 1] = qs; }
  } else {
    int row = (blockIdx.x - 512) * 4 + w;  // 0..2047
    xbuf[w][lane] = tgt[row * DT + lane];
    float a0 = 0.f, a1 = 0.f, a2_ = 0.f, a3 = 0.f;
#pragma unroll 4
    for (int k = 0; k < DT; k += 4) {
      a0  = fmaf(xbuf[w][k + 0], tW1[(k + 0) * HN + lane], a0);
      a1  = fmaf(xbuf[w][k + 1], tW1[(k + 1) * HN + lane], a1);
      a2_ = fmaf(xbuf[w][k + 2], tW1[(k + 2) * HN + lane], a2_);
      a3  = fmaf(xbuf[w][k + 3], tW1[(k + 3) * HN + lane], a3);
    }
    float h1 = ((a0 + a1) + (a2_ + a3)) + tb1[lane];
    float s1 = wave_sum(h1), s2 = wave_sum(h1 * h1);
    float m = s1 * (1.f / HN);
    float var = s2 * (1.f / HN) - m * m;
    float r = fmaxf(0.f, (h1 - m) * rsqrtf(var + LN_EPS) * tg[lane] + tbeta[lane]);
    rbuf[w][lane] = r;
    float b0 = 0.f, b1 = 0.f, b2 = 0.f, b3 = 0.f;
#pragma unroll 4
    for (int j = 0; j < HN; j += 4) {
      b0 = fmaf(rbuf[w][j + 0], tW2[(j + 0) * HN + lane], b0);
      b1 = fmaf(rbuf[w][j + 1], tW2[(j + 1) * HN + lane], b1);
      b2 = fmaf(rbuf[w][j + 2], tW2[(j + 2) * HN + lane], b2);
      b3 = fmaf(rbuf[w][j + 3], tW2[(j + 3) * HN + lane], b3);
    }
    float a2 = ((b0 + b1) + (b2 + b3)) + tb2[lane];
    t_ad[row * HN + lane] = a2;
    float asum = wave_sum(a2);
    float gate = 1.f / (1.f + __expf(-asum * (1.f / HN)));
    rbuf[w][lane] = a2;
    float c0 = 0.f, c1 = 0.f, c2 = 0.f, c3 = 0.f;
#pragma unroll 4
    for (int j = 0; j < HN; j += 4) {
      c0 = fmaf(rbuf[w][j + 0], cW[(j + 0) * HN + lane], c0);
      c1 = fmaf(rbuf[w][j + 1], cW[(j + 1) * HN + lane], c1);
      c2 = fmaf(rbuf[w][j + 2], cW[(j + 2) * HN + lane], c2);
      c3 = fmaf(rbuf[w][j + 3], cW[(j + 3) * HN + lane], c3);
    }
    float tcv = ((c0 + c1) + (c2 + c3)) + cb[lane];
    tc[row * HN + lane] = tcv;
    float A = wave_sum(tcv), Q = wave_sum(tcv * tcv);
    if (lane == 0) { tstats[row * 3] = A; tstats[row * 3 + 1] = Q; tstats[row * 3 + 2] = gate; }
  }
}

// ---------------- Kernel 2: scores v6 ----------------
// 8 waves = 8 t (one t/wave, consts via s_load). 256 s per block processed in
// 4 chunks of 64 s, double-buffered 2x16KB LDS: chunk c+1 global loads issue
// into VGPRs before computing chunk c (one barrier/chunk, no vmcnt drain at
// the barrier). Inner math written in float2 ext-vectors so clang can lower
// to v_pk_{fma,add,mul,max}_f32 (2 floats/lane/inst).
__global__ __launch_bounds__(512, 4) void k_scores(
    const float* __restrict__ cg, const float* __restrict__ cbeta,
    const float* __restrict__ simW, const float* __restrict__ simb,
    const float* __restrict__ sc, const float* __restrict__ sstats,
    const float* __restrict__ tc, const float* __restrict__ tstats,
    float* __restrict__ out_scores)
{
  __shared__ float tile[2][64 * 64];   // 2 x 16 KB
  int tid = threadIdx.x;
  int w = tid >> 6, lane = tid & 63;
  int sblk = blockIdx.x & 3;                 // 4 s-blocks of 256
  int tblk = (blockIdx.x >> 2) & 127;        // 128 t-blocks of 8
  int b    = blockIdx.x >> 9;
  int t = tblk * 8 + w;
  int rt = __builtin_amdgcn_readfirstlane(b * TN + t);

  float A  = tstats[rt * 3 + 0];
  float Qt = tstats[rt * 3 + 1];
  const float4* tcq = (const float4*)(tc + rt * HN);   // wave-uniform
  const float4* cgq = (const float4*)cg;
  const float4* cbq = (const float4*)cbeta;
  const float4* swq = (const float4*)simW;
  float simb0 = simb[0];

  const float4* scg = (const float4*)(sc + b * SN * HN);
  int s0 = sblk * 256;

  // staging-thread mapping: 2 float4 per thread per chunk
  int j0 = tid, j1 = 512 + tid;
  int r0 = j0 >> 4, g0 = j0 & 15;
  int r1 = j1 >> 4, g1 = j1 & 15;
  int d0 = r0 * 64 + ((g0 ^ (r0 & 15)) * 4);
  int d1 = r1 * 64 + ((g1 ^ (r1 & 15)) * 4);

  // prologue: chunk 0 -> buf 0
  {
    float4 v0 = scg[(s0 + r0) * 16 + g0];
    float4 v1 = scg[(s0 + r1) * 16 + g1];
    *(float4*)&tile[0][d0] = v0;
    *(float4*)&tile[0][d1] = v1;
  }
  __syncthreads();

#pragma unroll 1
  for (int c = 0; c < 4; ++c) {
    // prefetch chunk c+1 into regs (no wait until after compute)
    float4 p0, p1;
    if (c < 3) {
      int sn = s0 + (c + 1) * 64;
      p0 = scg[(sn + r0) * 16 + g0];
      p1 = scg[(sn + r1) * 16 + g1];
    }

    const float* tb_ = &tile[c & 1][0];
    int srow = lane;
    int s = s0 + c * 64 + lane;
    float2 bq = *(const float2*)&sstats[(b * SN + s) * 2];

    // pass 1: D = sum_h tc_h * sc_h   (packed)
    v2f D2 = {0.f, 0.f};
#pragma unroll
    for (int g = 0; g < 16; ++g) {
      float4 v = *(const float4*)&tb_[srow * 64 + ((g ^ (srow & 15)) * 4)];
      float4 t4 = tcq[g];
      v2f vlo = {v.x, v.y}, vhi = {v.z, v.w};
      v2f tlo = {t4.x, t4.y}, thi = {t4.z, t4.w};
      D2 = __builtin_elementwise_fma(tlo, vlo, D2);
      D2 = __builtin_elementwise_fma(thi, vhi, D2);
    }
    float D = D2.x + D2.y;
    float mean  = (A + bq.x) * (1.f / HN);
    float e2    = (Qt + bq.y + 2.f * D) * (1.f / HN);
    float var   = e2 - mean * mean;
    float alpha = rsqrtf(var + LN_EPS);

    v2f m2 = {mean, mean};
    v2f a2 = {alpha, alpha};
    v2f zero2 = {0.f, 0.f};
    v2f dot2 = {0.f, 0.f};

    // pass 2 (packed): n = ((sc+tc)-mean)*(alpha*cg)+cbeta; relu; dot simW
#pragma unroll
    for (int g = 0; g < 16; ++g) {
      float4 v  = *(const float4*)&tb_[srow * 64 + ((g ^ (srow & 15)) * 4)];
      float4 t4 = tcq[g];
      float4 c4 = cgq[g];
      float4 b4 = cbq[g];
      float4 w4 = swq[g];
      {
        v2f vv = {v.x, v.y}, tt = {t4.x, t4.y};
        v2f cc = {c4.x, c4.y}, bb = {b4.x, b4.y}, ss = {w4.x, w4.y};
        v2f u = vv + tt;
        v2f z = u - m2;
        v2f P = a2 * cc;
        v2f n = __builtin_elementwise_fma(z, P, bb);
        v2f r = __builtin_elementwise_max(n, zero2);
        dot2 = __builtin_elementwise_fma(r, ss, dot2);
      }
      {
        v2f vv = {v.z, v.w}, tt = {t4.z, t4.w};
        v2f cc = {c4.z, c4.w}, bb = {b4.z, b4.w}, ss = {w4.z, w4.w};
        v2f u = vv + tt;
        v2f z = u - m2;
        v2f P = a2 * cc;
        v2f n = __builtin_elementwise_fma(z, P, bb);
        v2f r = __builtin_elementwise_max(n, zero2);
        dot2 = __builtin_elementwise_fma(r, ss, dot2);
      }
    }
    float dot = dot2.x + dot2.y;
    float score = 1.f / (1.f + __expf(-(dot + simb0)));
    out_scores[rt * SN + s] = score;

    // write prefetched chunk into the other buffer, then barrier
    if (c < 3) {
      *(float4*)&tile[(c + 1) & 1][d0] = p0;
      *(float4*)&tile[(c + 1) & 1][d1] = p1;
    }
    __syncthreads();
  }
}

// ---------------- Kernel 3a: partial transfer (split-s) ----------------
__global__ __launch_bounds__(256, 4) void k_xfer(
    const float* __restrict__ scores, const float* __restrict__ s_ad,
    float* __restrict__ xpart, float* __restrict__ epart)
{
  __shared__ float eLDS[4][16][64];
  __shared__ float part[4][16][64];
  __shared__ float esum[4][16];
  int tid = threadIdx.x;
  int w = __builtin_amdgcn_readfirstlane(tid >> 6);
  int lane = tid & 63;
  int sblk = blockIdx.x & 3;
  int tblk = (blockIdx.x >> 2) & 63;
  int b    = blockIdx.x >> 8;
  int t0 = tblk * 16;
  int soff = sblk * 256 + w * 64;

#pragma unroll 4
  for (int t = 0; t < 16; ++t) {
    int rt = __builtin_amdgcn_readfirstlane(b * TN + t0 + t);
    float ev = __expf(scores[rt * SN + soff + lane]);
    eLDS[w][t][lane] = ev;
    float es = wave_sum(ev);
    if (lane == 0) esum[w][t] = es;
  }

  const float* sadb = s_ad + b * SN * HN;
  float acc[16];
#pragma unroll
  for (int t = 0; t < 16; ++t) acc[t] = 0.f;
#pragma unroll 4
  for (int si4 = 0; si4 < 16; ++si4) {
    int sbase = soff + si4 * 4;
    float sv0 = sadb[(sbase + 0) * HN + lane];
    float sv1 = sadb[(sbase + 1) * HN + lane];
    float sv2 = sadb[(sbase + 2) * HN + lane];
    float sv3 = sadb[(sbase + 3) * HN + lane];
#pragma unroll
    for (int t = 0; t < 16; ++t) {
      float4 e4 = *(const float4*)&eLDS[w][t][si4 * 4];
      acc[t] = fmaf(e4.x, sv0, acc[t]);
      acc[t] = fmaf(e4.y, sv1, acc[t]);
      acc[t] = fmaf(e4.z, sv2, acc[t]);
      acc[t] = fmaf(e4.w, sv3, acc[t]);
    }
  }

#pragma unroll
  for (int t = 0; t < 16; ++t) part[w][t][lane] = acc[t];
  __syncthreads();
#pragma unroll
  for (int k = 0; k < 4; ++k) {
    int c2 = tid + k * 256;
    int t = c2 >> 6, h = c2 & 63;
    float sum = part[0][t][h] + part[1][t][h] + part[2][t][h] + part[3][t][h];
    int rt = b * TN + t0 + t;
    xpart[(rt * 4 + sblk) * HN + h] = sum;
  }
  if (tid < 16) {
    float es = esum[0][tid] + esum[1][tid] + esum[2][tid] + esum[3][tid];
    int rt = b * TN + t0 + tid;
    epart[rt * 4 + sblk] = es;
  }
}

// ---------------- Kernel 3b: final combine + gate ----------------
__global__ __launch_bounds__(256) void k_final(
    const float* __restrict__ xpart, const float* __restrict__ epart,
    const float* __restrict__ t_ad, const float* __restrict__ tstats,
    float* __restrict__ out_adapted)
{
  int tid = threadIdx.x;
  int tl = tid >> 6, h = tid & 63;
  int rt = blockIdx.x * 4 + tl;       // 0..2047
  float x = xpart[(rt * 4 + 0) * HN + h] + xpart[(rt * 4 + 1) * HN + h]
          + xpart[(rt * 4 + 2) * HN + h] + xpart[(rt * 4 + 3) * HN + h];
  float es = epart[rt * 4 + 0] + epart[rt * 4 + 1]
           + epart[rt * 4 + 2] + epart[rt * 4 + 3];
  float tr = x / es;
  float gate = tstats[rt * 3 + 2];
  float tad = t_ad[rt * HN + h];
  out_adapted[rt * HN + h] = tad * (1.f - gate) + tr * gate;
}

extern "C" void kernel_launch(void* const* d_in, const int* in_sizes, int n_in,
                              void* d_out, int out_size, void* d_ws, size_t ws_size,
                              hipStream_t stream) {
  const float* src   = (const float*)d_in[0];
  const float* tgt   = (const float*)d_in[1];
  const float* sW1   = (const float*)d_in[2];
  const float* sb1   = (const float*)d_in[3];
  const float* sg    = (const float*)d_in[4];
  const float* sbeta = (const float*)d_in[5];
  const float* sW2   = (const float*)d_in[6];
  const float* sb2   = (const float*)d_in[7];
  const float* tW1   = (const float*)d_in[8];
  const float* tb1   = (const float*)d_in[9];
  const float* tg    = (const float*)d_in[10];
  const float* tbeta = (const float*)d_in[11];
  const float* tW2   = (const float*)d_in[12];
  const float* tb2   = (const float*)d_in[13];
  const float* cW    = (const float*)d_in[14];
  const float* cb    = (const float*)d_in[15];
  const float* cg    = (const float*)d_in[16];
  const float* cbeta = (const float*)d_in[17];
  const float* simW  = (const float*)d_in[18];
  const float* simb  = (const float*)d_in[19];

  float* ws     = (float*)d_ws;
  float* s_ad   = ws;               // 131072
  float* sc     = ws + 131072;      // 131072
  float* sstats = ws + 262144;      // 4096
  float* t_ad   = ws + 266240;      // 131072
  float* tc     = ws + 397312;      // 131072
  float* tstats = ws + 528384;      // 6144
  float* xpart  = ws + 534528;      // 524288
  float* epart  = ws + 1058816;     // 8192

  float* out_adapted = (float*)d_out;            // B*T*H
  float* out_scores  = (float*)d_out + 131072;   // B*T*S

  hipLaunchKernelGGL(k_adapters, dim3(1024), dim3(256), 0, stream,
                     src, tgt, sW1, sb1, sg, sbeta, sW2, sb2,
                     tW1, tb1, tg, tbeta, tW2, tb2, cW, cb,
                     s_ad, sc, sstats, t_ad, tc, tstats);
  hipLaunchKernelGGL(k_scores, dim3(BN * 128 * 4), dim3(512), 0, stream,
                     cg, cbeta, simW, simb, sc, sstats, tc, tstats, out_scores);
  hipLaunchKernelGGL(k_xfer, dim3(BN * 64 * 4), dim3(256), 0, stream,
                     out_scores, s_ad, xpart, epart);
  hipLaunchKernelGGL(k_final, dim3(512), dim3(256), 0, stream,
                     xpart, epart, t_ad, tstats, out_adapted);
}